// Round 5
// baseline (203.754 us; speedup 1.0000x reference)
//
#include <hip/hip_runtime.h>
#include <hip/hip_bf16.h>

typedef __attribute__((ext_vector_type(8))) short bf16x8;
typedef __attribute__((ext_vector_type(4))) float f32x4;

#define NCOLP 384                 // padded columns (352 real + 32 zero)
#define STEP_SHORTS (NCOLP * 32)  // 12288 shorts = 24576 B per 32-k step
#define STEP_BYTES 24576
#define SEG_BYTES 6144            // per-ablk segment: 384 cols * 8k * 2B
#define NSTEP 32
#define BROWS 65536
#define A_SLOT 16384              // 128 rows * 128 B (32 fp32) per k-step

static __device__ __forceinline__ unsigned int bf16rne(float f) {
  unsigned int u = __float_as_uint(f);
  return (u + 0x7FFFu + ((u >> 16) & 1u)) >> 16;
}
static __device__ __forceinline__ unsigned int pack2(float a, float b) {
  return bf16rne(a) | (bf16rne(b) << 16);
}
static __device__ __forceinline__ void gload16(const void* g, void* l) {
  __builtin_amdgcn_global_load_lds(
      (const __attribute__((address_space(1))) unsigned int*)g,
      (__attribute__((address_space(3))) unsigned int*)l, 16, 0, 0);
}

// Wpack layout: [step][ablk(4)][col(384)][k%8]  (bf16), step = 24576 B.
// Column map: [0,100) task0 (e*10+h), [100,200) task1, [200,300) shared,
// [300,340) gates (t*20+g), [340,384) zero pad.
__global__ void ple_prep(const float* __restrict__ Ws, const float* __restrict__ bs,
                         const float* __restrict__ Wt, const float* __restrict__ bt,
                         const float* __restrict__ Wg, const float* __restrict__ bg,
                         unsigned short* __restrict__ Wpack, float* __restrict__ bias) {
  const int n = blockIdx.x;  // 0..383
  const int tid = threadIdx.x;
  const float* src = nullptr;
  int stride = 0;
  float bval = 0.f;
  if (n < 200) {
    int t = n / 100, m = n % 100, e = m / 10, h = m % 10;
    src = Wt + (size_t)(t * 10 + e) * 10240 + h;
    stride = 10;
    bval = bt[(t * 10 + e) * 10 + h];
  } else if (n < 300) {
    int m = n - 200, e = m / 10, h = m % 10;
    src = Ws + (size_t)e * 10240 + h;
    stride = 10;
    bval = bs[e * 10 + h];
  } else if (n < 340) {
    int m = n - 300, t = m / 20, g = m % 20;
    src = Wg + (size_t)t * 20480 + g;
    stride = 20;
    bval = bg[t * 20 + g];
  }
  for (int j = 0; j < 4; j++) {
    int k = tid + j * 256;
    float v = src ? src[(size_t)k * stride] : 0.f;
    Wpack[(size_t)(k >> 5) * STEP_SHORTS + ((k >> 3) & 3) * (NCOLP * 8) + n * 8 +
          (k & 7)] = (unsigned short)bf16rne(v);
  }
  if (tid == 0 && n < 352) bias[n] = bval;
}

// Main: 512 threads = 8 waves (2M x 4N), 128 rows/block.
// A: global -> LDS (2-slot ring, global_load_lds, XOR slot-swizzle via
// pre-swizzled per-lane SOURCE address, fp32 in LDS, cvt on read).
// B: per-lane register loads from L2-resident Wpack (no LDS).
__global__ __launch_bounds__(512, 2) void ple_main(
    const float* __restrict__ x, const unsigned short* __restrict__ Wpack,
    const float* __restrict__ bias, const float* __restrict__ Wc,
    const float* __restrict__ bc, const float* __restrict__ Wv,
    const float* __restrict__ bv, float* __restrict__ out) {
  __shared__ __align__(16) char smem[45696];  // 2*A_SLOT ring; z[32][357] aliases
  float* z = (float*)smem;

  const int tid = threadIdx.x;
  const int l = tid & 63, w = tid >> 6;
  const int wm = w >> 2, wn = w & 3;  // 2M x 4N
  const int arow = l & 15, ablk = l >> 4;
  const int rowbase = blockIdx.x * 128;

  const f32x4 fzero = {0.f, 0.f, 0.f, 0.f};
  f32x4 acc[4][6];
#pragma unroll
  for (int i = 0; i < 4; ++i)
#pragma unroll
    for (int j = 0; j < 6; ++j) acc[i][j] = fzero;

  // ---- A staging addresses (2 glds per thread per iter) ----
  // LDS linear idx = j*512 + tid (16B units); row = idx>>3, s' = tid&7.
  // Logical slot s = s' ^ (row&7); global src = row*4096 + ks*128 + s*16.
  const char* xb = (const char*)x;
  const int idx0 = tid, idx1 = 512 + tid;
  const int row0 = idx0 >> 3, row1 = idx1 >> 3;
  const int sl0 = (tid & 7) ^ (row0 & 7), sl1 = (tid & 7) ^ (row1 & 7);
  const char* asrc0 = xb + (size_t)(rowbase + row0) * 4096 + sl0 * 16;
  const char* asrc1 = xb + (size_t)(rowbase + row1) * 4096 + sl1 * 16;
  char* adst0 = smem + idx0 * 16;  // + slot*A_SLOT
  char* adst1 = smem + idx1 * 16;

  // ---- A fragment read offsets (per mf: 2x ds_read_b128) ----
  // row_local = wm*64 + mf*16 + arow; s'h = (ablk*2+h) ^ (arow&7)
  const int sp0 = ((ablk * 2) ^ (arow & 7)) * 16;
  const int sp1 = ((ablk * 2 + 1) ^ (arow & 7)) * 16;
  const int arbase = (wm * 64 + arow) * 128;

  // ---- B fragment base (per-lane, 16B) ----
  const char* bbase = (const char*)Wpack + ablk * SEG_BYTES +
                      (wn * 96 + arow) * 16;

  bf16x8 b[2][6];

  // ---- prologue: stage A(0) -> slot 0; load B(0) -> b[0] ----
  gload16(asrc0, adst0);
  gload16(asrc1, adst1);
  __builtin_amdgcn_sched_barrier(0);
#pragma unroll
  for (int nt = 0; nt < 6; nt++)
    b[0][nt] = *(const bf16x8*)(bbase + nt * 256);
  __builtin_amdgcn_sched_barrier(0);

#pragma unroll 2
  for (int ks = 0; ks < NSTEP; ks++) {
    const int cur = ks & 1;
    // (a) stage A(ks+1) -> slot cur^1   [2 vmem]
    {
      const int ksA = (ks + 1 < NSTEP) ? ks + 1 : NSTEP - 1;
      const size_t so = (size_t)(cur ^ 1) * A_SLOT;
      gload16(asrc0 + ksA * 128, adst0 + so);
      gload16(asrc1 + ksA * 128, adst1 + so);
    }
    __builtin_amdgcn_sched_barrier(0);
    // (b) prefetch B(ks+1) -> b[cur^1]  [6 vmem]
    {
      const int ksB = (ks + 1 < NSTEP) ? ks + 1 : NSTEP - 1;
      const char* bp = bbase + (size_t)ksB * STEP_BYTES;
#pragma unroll
      for (int nt = 0; nt < 6; nt++)
        b[cur ^ 1][nt] = *(const bf16x8*)(bp + nt * 256);
    }
    __builtin_amdgcn_sched_barrier(0);
    // (c) exactly 8 vmem issued this iter -> stage A(ks) & B(ks) complete
    asm volatile("s_waitcnt vmcnt(8)" ::: "memory");
    __builtin_amdgcn_s_barrier();
    __builtin_amdgcn_sched_barrier(0);
    // (d) ds_read A frags from slot cur, cvt, MFMA with b[cur]
    {
      const char* ab = smem + (size_t)cur * A_SLOT + arbase;
#pragma unroll
      for (int mf = 0; mf < 4; mf++) {
        float4 fa = *(const float4*)(ab + mf * 2048 + sp0);
        float4 fb = *(const float4*)(ab + mf * 2048 + sp1);
        union { bf16x8 v; uint4 u; } A;
        A.u = make_uint4(pack2(fa.x, fa.y), pack2(fa.z, fa.w),
                         pack2(fb.x, fb.y), pack2(fb.z, fb.w));
#pragma unroll
        for (int nt = 0; nt < 6; nt++)
          acc[mf][nt] =
              __builtin_amdgcn_mfma_f32_16x16x32_bf16(A.v, b[cur][nt], acc[mf][nt], 0, 0, 0);
      }
    }
    __builtin_amdgcn_sched_barrier(0);
    // (e) reads of slot cur done before next iter overwrites it
    __builtin_amdgcn_s_barrier();
  }

  // ---- epilogue: 4 phases of 32 rows. D layout: row=(l>>4)*4+reg, col=l&15.
  for (int p = 0; p < 4; p++) {
    __syncthreads();
    if (wm == (p >> 1)) {
#pragma unroll
      for (int q = 0; q < 2; q++) {
        const int mf = (p & 1) * 2 + q;
#pragma unroll
        for (int nt = 0; nt < 6; nt++) {
          if (wn == 3 && nt >= 4) continue;  // cols >= 352 are zero pad
#pragma unroll
          for (int r = 0; r < 4; r++)
            z[(q * 16 + ablk * 4 + r) * 357 + wn * 96 + nt * 16 + arow] =
                acc[mf][nt][r];
        }
      }
    }
    __syncthreads();
    if (tid < 64) {
      const int t = tid >> 5, r = tid & 31;
      const float* zr = &z[r * 357];
      float gl[20], m = -1e30f;
#pragma unroll
      for (int u = 0; u < 20; u++) {
        gl[u] = zr[300 + t * 20 + u] + bias[300 + t * 20 + u];
        m = fmaxf(m, gl[u]);
      }
      float pr[20], s = 0.f;
#pragma unroll
      for (int u = 0; u < 20; u++) {
        pr[u] = __expf(gl[u] - m);
        s += pr[u];
      }
      const float inv = 1.f / s;
      const float* Wl = t ? Wv : Wc;
      float wl[10];
#pragma unroll
      for (int h = 0; h < 10; h++) wl[h] = Wl[h];
      float accum = 0.f;
#pragma unroll
      for (int u = 0; u < 10; u++) {
        float d = 0.f;
#pragma unroll
        for (int h = 0; h < 10; h++) {
          int c = t * 100 + u * 10 + h;
          d += fmaxf(zr[c] + bias[c], 0.f) * wl[h];
        }
        accum += pr[u] * d;
      }
#pragma unroll
      for (int u = 0; u < 10; u++) {
        float d = 0.f;
#pragma unroll
        for (int h = 0; h < 10; h++) {
          int c = 200 + u * 10 + h;
          d += fmaxf(zr[c] + bias[c], 0.f) * wl[h];
        }
        accum += pr[10 + u] * d;
      }
      float logit = (t ? bv[0] : bc[0]) + accum * inv;
      out[(size_t)t * BROWS + rowbase + p * 32 + r] =
          1.f / (1.f + __expf(-logit));
    }
  }
}

extern "C" void kernel_launch(void* const* d_in, const int* in_sizes, int n_in,
                              void* d_out, int out_size, void* d_ws, size_t ws_size,
                              hipStream_t stream) {
  const float* x = (const float*)d_in[0];
  const float* Ws = (const float*)d_in[3];
  const float* bs = (const float*)d_in[4];
  const float* Wt = (const float*)d_in[5];
  const float* bt = (const float*)d_in[6];
  const float* Wg = (const float*)d_in[7];
  const float* bg = (const float*)d_in[8];
  const float* Wc = (const float*)d_in[9];
  const float* bc = (const float*)d_in[10];
  const float* Wv = (const float*)d_in[11];
  const float* bv = (const float*)d_in[12];
  unsigned short* Wpack = (unsigned short*)d_ws;
  float* bias = (float*)((char*)d_ws + (size_t)NCOLP * 1024 * 2);
  float* out = (float*)d_out;

  hipLaunchKernelGGL(ple_prep, dim3(NCOLP), dim3(256), 0, stream, Ws, bs, Wt, bt,
                     Wg, bg, Wpack, bias);
  hipLaunchKernelGGL(ple_main, dim3(BROWS / 128), dim3(512), 0, stream, x, Wpack,
                     bias, Wc, bc, Wv, bv, out);
}

// Round 6
// 153.897 us; speedup vs baseline: 1.3240x; 1.3240x over previous
//
#include <hip/hip_runtime.h>
#include <hip/hip_bf16.h>

typedef __attribute__((ext_vector_type(8))) short bf16x8;
typedef __attribute__((ext_vector_type(4))) float f32x4;

#define NCOLP 384                 // padded columns (352 real + 32 zero)
#define STEP_SHORTS (NCOLP * 32)  // 12288 shorts = 24576 B per 32-k step
#define STEP_BYTES 24576
#define SEG_BYTES 6144            // per-ablk segment: 384 cols * 8k * 2B
#define NSTEP 32
#define BROWS 65536
#define A_SLOT 16384              // 128 rows * 128 B (32 fp32) per k-step

static __device__ __forceinline__ unsigned int bf16rne(float f) {
  unsigned int u = __float_as_uint(f);
  return (u + 0x7FFFu + ((u >> 16) & 1u)) >> 16;
}
static __device__ __forceinline__ unsigned int pack2(float a, float b) {
  return bf16rne(a) | (bf16rne(b) << 16);
}
static __device__ __forceinline__ void gload16(const void* g, void* l) {
  __builtin_amdgcn_global_load_lds(
      (const __attribute__((address_space(1))) unsigned int*)g,
      (__attribute__((address_space(3))) unsigned int*)l, 16, 0, 0);
}

// Wpack layout: [step][ablk(4)][col(384)][k%8]  (bf16), step = 24576 B.
// Column map: [0,100) task0 (e*10+h), [100,200) task1, [200,300) shared,
// [300,340) gates (t*20+g), [340,384) zero pad.
__global__ void ple_prep(const float* __restrict__ Ws, const float* __restrict__ bs,
                         const float* __restrict__ Wt, const float* __restrict__ bt,
                         const float* __restrict__ Wg, const float* __restrict__ bg,
                         unsigned short* __restrict__ Wpack, float* __restrict__ bias) {
  const int n = blockIdx.x;  // 0..383
  const int tid = threadIdx.x;
  const float* src = nullptr;
  int stride = 0;
  float bval = 0.f;
  if (n < 200) {
    int t = n / 100, m = n % 100, e = m / 10, h = m % 10;
    src = Wt + (size_t)(t * 10 + e) * 10240 + h;
    stride = 10;
    bval = bt[(t * 10 + e) * 10 + h];
  } else if (n < 300) {
    int m = n - 200, e = m / 10, h = m % 10;
    src = Ws + (size_t)e * 10240 + h;
    stride = 10;
    bval = bs[e * 10 + h];
  } else if (n < 340) {
    int m = n - 300, t = m / 20, g = m % 20;
    src = Wg + (size_t)t * 20480 + g;
    stride = 20;
    bval = bg[t * 20 + g];
  }
  for (int j = 0; j < 4; j++) {
    int k = tid + j * 256;
    float v = src ? src[(size_t)k * stride] : 0.f;
    Wpack[(size_t)(k >> 5) * STEP_SHORTS + ((k >> 3) & 3) * (NCOLP * 8) + n * 8 +
          (k & 7)] = (unsigned short)bf16rne(v);
  }
  if (tid == 0 && n < 352) bias[n] = bval;
}

// Main: 512 threads = 8 waves (2M x 4N), 128 rows/block.
// A: global -> LDS (2-slot ring, global_load_lds, XOR slot-swizzle via
// pre-swizzled per-lane SOURCE address, fp32 in LDS, cvt on read).
// B: per-lane register loads from L2-resident Wpack (no LDS).
// ALL register arrays statically indexed (rule #20): K-loop body is a
// macro with literal cur; epilogue p-loop fully unrolled.
__global__ __launch_bounds__(512, 2) void ple_main(
    const float* __restrict__ x, const unsigned short* __restrict__ Wpack,
    const float* __restrict__ bias, const float* __restrict__ Wc,
    const float* __restrict__ bc, const float* __restrict__ Wv,
    const float* __restrict__ bv, float* __restrict__ out) {
  __shared__ __align__(16) char smem[45696];  // 2*A_SLOT ring; z[32][357] aliases
  float* z = (float*)smem;

  const int tid = threadIdx.x;
  const int l = tid & 63, w = tid >> 6;
  const int wm = w >> 2, wn = w & 3;  // 2M x 4N
  const int arow = l & 15, ablk = l >> 4;
  const int rowbase = blockIdx.x * 128;

  const f32x4 fzero = {0.f, 0.f, 0.f, 0.f};
  f32x4 acc[4][6];
#pragma unroll
  for (int i = 0; i < 4; ++i)
#pragma unroll
    for (int j = 0; j < 6; ++j) acc[i][j] = fzero;

  // ---- A staging addresses (2 glds per thread per iter) ----
  // LDS linear idx = j*512 + tid (16B units); row = idx>>3, s' = tid&7.
  // Logical slot s = s' ^ (row&7); global src = row*4096 + ks*128 + s*16.
  const char* xb = (const char*)x;
  const int idx0 = tid, idx1 = 512 + tid;
  const int row0 = idx0 >> 3, row1 = idx1 >> 3;
  const int sl0 = (tid & 7) ^ (row0 & 7), sl1 = (tid & 7) ^ (row1 & 7);
  const char* asrc0 = xb + (size_t)(rowbase + row0) * 4096 + sl0 * 16;
  const char* asrc1 = xb + (size_t)(rowbase + row1) * 4096 + sl1 * 16;
  char* adst0 = smem + idx0 * 16;  // + slot*A_SLOT
  char* adst1 = smem + idx1 * 16;

  // ---- A fragment read offsets (per mf: 2x ds_read_b128) ----
  // row_local = wm*64 + mf*16 + arow; s'h = (ablk*2+h) ^ (arow&7)
  const int sp0 = ((ablk * 2) ^ (arow & 7)) * 16;
  const int sp1 = ((ablk * 2 + 1) ^ (arow & 7)) * 16;
  const int arbase = (wm * 64 + arow) * 128;

  // ---- B fragment base (per-lane, 16B) ----
  const char* bbase = (const char*)Wpack + ablk * SEG_BYTES +
                      (wn * 96 + arow) * 16;

  bf16x8 b0[6], b1[6];  // two named banks (static indexing only)

  // ---- prologue: stage A(0) -> slot 0; load B(0) -> b0 ----
  gload16(asrc0, adst0);
  gload16(asrc1, adst1);
  __builtin_amdgcn_sched_barrier(0);
#pragma unroll
  for (int nt = 0; nt < 6; nt++)
    b0[nt] = *(const bf16x8*)(bbase + nt * 256);
  __builtin_amdgcn_sched_barrier(0);

  // K-step body: CUR = literal 0/1. bc_ = bank holding B(ks), bn_ = other.
#define KSTEP(ks, CUR, bc_, bn_)                                               \
  {                                                                            \
    const int ksA = ((ks) + 1 < NSTEP) ? (ks) + 1 : NSTEP - 1;                 \
    const size_t so = (size_t)((CUR) ^ 1) * A_SLOT;                            \
    gload16(asrc0 + ksA * 128, adst0 + so);                                    \
    gload16(asrc1 + ksA * 128, adst1 + so);                                    \
    __builtin_amdgcn_sched_barrier(0);                                         \
    const char* bp = bbase + (size_t)ksA * STEP_BYTES;                         \
    _Pragma("unroll") for (int nt = 0; nt < 6; nt++)                           \
        bn_[nt] = *(const bf16x8*)(bp + nt * 256);                             \
    __builtin_amdgcn_sched_barrier(0);                                         \
    asm volatile("s_waitcnt vmcnt(8)" ::: "memory");                           \
    __builtin_amdgcn_s_barrier();                                              \
    __builtin_amdgcn_sched_barrier(0);                                         \
    const char* ab = smem + (size_t)(CUR)*A_SLOT + arbase;                     \
    _Pragma("unroll") for (int mf = 0; mf < 4; mf++) {                         \
      float4 fa = *(const float4*)(ab + mf * 2048 + sp0);                      \
      float4 fb = *(const float4*)(ab + mf * 2048 + sp1);                      \
      union { bf16x8 v; uint4 u; } A;                                          \
      A.u = make_uint4(pack2(fa.x, fa.y), pack2(fa.z, fa.w),                   \
                       pack2(fb.x, fb.y), pack2(fb.z, fb.w));                  \
      _Pragma("unroll") for (int nt = 0; nt < 6; nt++)                         \
          acc[mf][nt] = __builtin_amdgcn_mfma_f32_16x16x32_bf16(               \
              A.v, bc_[nt], acc[mf][nt], 0, 0, 0);                             \
    }                                                                          \
    __builtin_amdgcn_sched_barrier(0);                                         \
    __builtin_amdgcn_s_barrier();                                              \
  }

  for (int kk = 0; kk < NSTEP / 2; kk++) {
    KSTEP(2 * kk, 0, b0, b1)
    KSTEP(2 * kk + 1, 1, b1, b0)
  }
#undef KSTEP

  // ---- epilogue: 4 phases of 32 rows, FULLY UNROLLED (static acc idx).
  // D layout: row=(l>>4)*4+reg, col=l&15.
#pragma unroll
  for (int p = 0; p < 4; p++) {
    __syncthreads();
    if (wm == (p >> 1)) {
#pragma unroll
      for (int q = 0; q < 2; q++) {
        const int mf = (p & 1) * 2 + q;
#pragma unroll
        for (int nt = 0; nt < 6; nt++) {
          if (wn == 3 && nt >= 4) continue;  // cols >= 352 are zero pad
#pragma unroll
          for (int r = 0; r < 4; r++)
            z[(q * 16 + ablk * 4 + r) * 357 + wn * 96 + nt * 16 + arow] =
                acc[mf][nt][r];
        }
      }
    }
    __syncthreads();
    if (tid < 64) {
      const int t = tid >> 5, r = tid & 31;
      const float* zr = &z[r * 357];
      float gl[20], m = -1e30f;
#pragma unroll
      for (int u = 0; u < 20; u++) {
        gl[u] = zr[300 + t * 20 + u] + bias[300 + t * 20 + u];
        m = fmaxf(m, gl[u]);
      }
      float pr[20], s = 0.f;
#pragma unroll
      for (int u = 0; u < 20; u++) {
        pr[u] = __expf(gl[u] - m);
        s += pr[u];
      }
      const float inv = 1.f / s;
      const float* Wl = t ? Wv : Wc;
      float wl[10];
#pragma unroll
      for (int h = 0; h < 10; h++) wl[h] = Wl[h];
      float accum = 0.f;
#pragma unroll
      for (int u = 0; u < 10; u++) {
        float d = 0.f;
#pragma unroll
        for (int h = 0; h < 10; h++) {
          int c = t * 100 + u * 10 + h;
          d += fmaxf(zr[c] + bias[c], 0.f) * wl[h];
        }
        accum += pr[u] * d;
      }
#pragma unroll
      for (int u = 0; u < 10; u++) {
        float d = 0.f;
#pragma unroll
        for (int h = 0; h < 10; h++) {
          int c = 200 + u * 10 + h;
          d += fmaxf(zr[c] + bias[c], 0.f) * wl[h];
        }
        accum += pr[10 + u] * d;
      }
      float logit = (t ? bv[0] : bc[0]) + accum * inv;
      out[(size_t)t * BROWS + rowbase + p * 32 + r] =
          1.f / (1.f + __expf(-logit));
    }
  }
}

extern "C" void kernel_launch(void* const* d_in, const int* in_sizes, int n_in,
                              void* d_out, int out_size, void* d_ws, size_t ws_size,
                              hipStream_t stream) {
  const float* x = (const float*)d_in[0];
  const float* Ws = (const float*)d_in[3];
  const float* bs = (const float*)d_in[4];
  const float* Wt = (const float*)d_in[5];
  const float* bt = (const float*)d_in[6];
  const float* Wg = (const float*)d_in[7];
  const float* bg = (const float*)d_in[8];
  const float* Wc = (const float*)d_in[9];
  const float* bc = (const float*)d_in[10];
  const float* Wv = (const float*)d_in[11];
  const float* bv = (const float*)d_in[12];
  unsigned short* Wpack = (unsigned short*)d_ws;
  float* bias = (float*)((char*)d_ws + (size_t)NCOLP * 1024 * 2);
  float* out = (float*)d_out;

  hipLaunchKernelGGL(ple_prep, dim3(NCOLP), dim3(256), 0, stream, Ws, bs, Wt, bt,
                     Wg, bg, Wpack, bias);
  hipLaunchKernelGGL(ple_main, dim3(BROWS / 128), dim3(512), 0, stream, x, Wpack,
                     bias, Wc, bc, Wv, bv, out);
}